// Round 2
// baseline (510.626 us; speedup 1.0000x reference)
//
#include <hip/hip_runtime.h>

typedef unsigned int uint;
typedef unsigned short ushort;
typedef float __attribute__((ext_vector_type(4))) f32x4;

// ============================================================================
// Kernel 1: per-(n,c) cube (64^3 f32 = 1 MB) -> xd[64], xh[64], xw[64] means.
// 1024 threads: t = h*16 + w4 (w4 = w-quad). Each thread loops d, one float4
// per iter (index d*1024 + t -> fully coalesced).
// pool layout (f32, in d_ws): [n][l][c]; l: 0..63 = d-means, 64..127 = h,
// 128..191 = w. Transposed so kernel 2 reads rows with float4.
// NOTE: x loads here are REGULAR (not nt) on purpose — this pass populates
// the 256 MiB Infinity Cache with x so att_k's second read hits L3.
// ============================================================================
__global__ __launch_bounds__(1024) void pool_k(const float* __restrict__ x,
                                               float* __restrict__ pool) {
    const int blk = blockIdx.x;          // n*64 + c
    const int t = threadIdx.x;
    __shared__ float sd[64], sh[64], sw[64];
    if (t < 64) { sd[t] = 0.f; sh[t] = 0.f; sw[t] = 0.f; }
    __syncthreads();

    const int w4 = t & 15;               // w-quad: covers w = w4*4 .. +3
    const int h  = t >> 4;               // 0..63
    const float4* __restrict__ xp = (const float4*)(x + (size_t)blk * 262144);

    float accw[4] = {0,0,0,0};
    float acch = 0.f;

    #pragma unroll 4
    for (int d = 0; d < 64; ++d) {
        float4 v = xp[d * 1024 + t];
        accw[0] += v.x; accw[1] += v.y; accw[2] += v.z; accw[3] += v.w;
        float s = (v.x + v.y) + (v.z + v.w);
        acch += s;
        // wave-64 reduce s -> one LDS atomic per wave per d
        float r = s;
        r += __shfl_down(r, 32);
        r += __shfl_down(r, 16);
        r += __shfl_down(r, 8);
        r += __shfl_down(r, 4);
        r += __shfl_down(r, 2);
        r += __shfl_down(r, 1);
        if ((t & 63) == 0) atomicAdd(&sd[d], r);
    }
    atomicAdd(&sh[h], acch);
    #pragma unroll
    for (int j = 0; j < 4; ++j) atomicAdd(&sw[w4 * 4 + j], accw[j]);
    __syncthreads();

    if (t < 192) {
        float v = (t < 64) ? sd[t] : (t < 128) ? sh[t - 64] : sw[t - 128];
        const int n = blk >> 6, c = blk & 63;
        pool[(n * 192 + t) * 64 + c] = v * (1.0f / 4096.0f);
    }
}

// ============================================================================
// Kernel 2: per-(n,c) block. Stage A/B: recompute the tiny attention chain
// -> 192 gate values in LDS. Stage C: stream the cube:
// out = x * a[d] * a[64+h] * a[128+w]   (all f32).
// Stage C: REGULAR loads for x (so the re-read can HIT the x lines pool_k
// left in the Infinity Cache — nt loads appear to bypass the L3 lookup) and
// NON-TEMPORAL stores for out (never re-read; must not evict x from L3).
// ============================================================================
__global__ __launch_bounds__(1024) void att_k(
    const float* __restrict__ x, const float* __restrict__ pool,
    const float* __restrict__ w1, const float* __restrict__ b1,
    const float* __restrict__ gam, const float* __restrict__ bet,
    const float* __restrict__ mu,  const float* __restrict__ var,
    const float* __restrict__ wd,  const float* __restrict__ bd,
    const float* __restrict__ wh,  const float* __restrict__ bh,
    const float* __restrict__ ww,  const float* __restrict__ bw,
    float* __restrict__ out)
{
    const int blk = blockIdx.x;
    const int n = blk >> 6, c = blk & 63;
    const int t = threadIdx.x;
    __shared__ float y_s[8][192];
    __shared__ float a_s[192];

    // ---- Stage A: y[m][l] = hardswish(BN(conv1(pool))) ----
    if (t < 192) {
        float acc[8] = {0,0,0,0,0,0,0,0};
        const float4* __restrict__ pp = (const float4*)(pool + (n * 192 + t) * 64);
        #pragma unroll 4
        for (int c4 = 0; c4 < 16; ++c4) {
            float4 p = pp[c4];
            const int cb = c4 * 4;
            #pragma unroll
            for (int m = 0; m < 8; ++m) {
                acc[m] += p.x * w1[m * 64 + cb]
                        + p.y * w1[m * 64 + cb + 1]
                        + p.z * w1[m * 64 + cb + 2]
                        + p.w * w1[m * 64 + cb + 3];
            }
        }
        #pragma unroll
        for (int m = 0; m < 8; ++m) {
            float scale = gam[m] * rsqrtf(var[m] + 1e-5f);
            float v = (acc[m] + b1[m] - mu[m]) * scale + bet[m];
            float hs = v * fminf(fmaxf(v + 3.0f, 0.0f), 6.0f) * (1.0f / 6.0f);
            y_s[m][t] = hs;
        }
    }
    __syncthreads();

    // ---- Stage B: gates a[l] = sigmoid(conv{d,h,w}(y)[o=c]) ----
    if (t < 192) {
        const float* wsel; float bsel;
        if (t < 64)       { wsel = wd + c * 8; bsel = bd[c]; }
        else if (t < 128) { wsel = wh + c * 8; bsel = bh[c]; }
        else              { wsel = ww + c * 8; bsel = bw[c]; }
        float v = bsel;
        #pragma unroll
        for (int m = 0; m < 8; ++m) v += y_s[m][t] * wsel[m];
        a_s[t] = 1.0f / (1.0f + __expf(-v));
    }
    __syncthreads();

    // ---- Stage C: out = x * ad*ah*aw, streamed (f32 in, f32 out) ----
    // float4 group g = t + k*1024: w4 = t&15, h = t>>4 loop-invariant; d = k.
    const int w4 = t & 15;
    const int h  = t >> 4;
    f32x4 gw;
    gw.x = a_s[128 + w4 * 4 + 0];
    gw.y = a_s[128 + w4 * 4 + 1];
    gw.z = a_s[128 + w4 * 4 + 2];
    gw.w = a_s[128 + w4 * 4 + 3];
    const float ahr = a_s[64 + h];
    const f32x4* __restrict__ xp = (const f32x4*)(x   + (size_t)blk * 262144);
    f32x4*       __restrict__ op = (f32x4*)      (out + (size_t)blk * 262144);

    #pragma unroll 2
    for (int k = 0; k < 64; ++k) {
        const int g = t + (k << 10);
        const float s = a_s[k] * ahr;        // a_s[d], d == k (uniform)
        f32x4 v = xp[g];                     // REGULAR load: want the L3 hit
        f32x4 o = v * (gw * s);
        __builtin_nontemporal_store(o, &op[g]);
    }
}

extern "C" void kernel_launch(void* const* d_in, const int* in_sizes, int n_in,
                              void* d_out, int out_size, void* d_ws, size_t ws_size,
                              hipStream_t stream) {
    const float* x = (const float*)d_in[0];
    float* pool = (float*)d_ws;   // 4*192*64 f32 = 192 KiB

    pool_k<<<256, 1024, 0, stream>>>(x, pool);
    att_k<<<256, 1024, 0, stream>>>(x, pool,
        (const float*)d_in[1],  (const float*)d_in[2],
        (const float*)d_in[3],  (const float*)d_in[4],
        (const float*)d_in[5],  (const float*)d_in[6],
        (const float*)d_in[7],  (const float*)d_in[8],
        (const float*)d_in[9],  (const float*)d_in[10],
        (const float*)d_in[11], (const float*)d_in[12],
        (float*)d_out);
}

// Round 3
// 508.784 us; speedup vs baseline: 1.0036x; 1.0036x over previous
//
#include <hip/hip_runtime.h>

typedef unsigned int uint;
typedef unsigned short ushort;
typedef float __attribute__((ext_vector_type(4))) f32x4;

// ============================================================================
// Kernel 1: per-(n,c) cube (64^3 f32 = 1 MB) -> xd[64], xh[64], xw[64] means.
// 1024 threads = 16 waves. Wave wv owns d-slices {wv, 16+wv, 32+wv, 48+wv}.
// Inner (j,k): lane l reads float4 at slice_d + j*64 + l  -> 1 KiB/wave/instr,
// fully coalesced. Reduction geometry chosen to minimize DS ops:
//   sd: per-slice register accum -> one 6-shfl wave reduce per d (24 shfl,
//       4 plain stores -- wave-exclusive, no atomics, no init).
//   sh: h = j*4+g is 16-lane-subgroup-uniform -> 4x shfl_xor per j + 1 atomic.
//   sw: register accum across whole cube -> 2 shfl + atomic, x4 at end.
// ~120 DS wave-ops/wave vs 448 in the per-d-shuffle version.
// pool layout (f32, in d_ws): [n][l][c]; l: 0..63 = d, 64..127 = h,
// 128..191 = w. Transposed so kernel 2 reads rows with float4.
// x loads REGULAR (not nt): this pass warms the Infinity Cache for att_k.
// ============================================================================
__global__ __launch_bounds__(1024) void pool_k(const float* __restrict__ x,
                                               float* __restrict__ pool) {
    const int blk = blockIdx.x;          // n*64 + c
    const int t  = threadIdx.x;
    const int wv = t >> 6;               // wave 0..15
    const int l  = t & 63;               // lane
    const int g  = l >> 4;               // 0..3  (h-subgroup)
    const int w4 = l & 15;               // w-quad
    __shared__ float sd[64], sh[64], sw[64];
    if (t < 64) { sh[t] = 0.f; sw[t] = 0.f; }
    __syncthreads();

    const float4* __restrict__ xp = (const float4*)(x + (size_t)blk * 262144);
    const float4* __restrict__ base = xp + wv * 1024 + l;

    float accd[4] = {0,0,0,0};           // per owned d-slice
    float accw[4] = {0,0,0,0};           // per w-in-quad component

    #pragma unroll 4
    for (int j = 0; j < 16; ++j) {       // h-row-quad within slice
        float acch = 0.f;
        #pragma unroll
        for (int k = 0; k < 4; ++k) {    // which owned slice (d = k*16+wv)
            float4 v = base[k * 16384 + j * 64];
            accw[0] += v.x; accw[1] += v.y; accw[2] += v.z; accw[3] += v.w;
            float s = (v.x + v.y) + (v.z + v.w);
            accd[k] += s;
            acch += s;
        }
        // reduce over the 16-lane w4 subgroup (h = j*4 + g is uniform there)
        acch += __shfl_xor(acch, 1);
        acch += __shfl_xor(acch, 2);
        acch += __shfl_xor(acch, 4);
        acch += __shfl_xor(acch, 8);
        if (w4 == 0) atomicAdd(&sh[j * 4 + g], acch);
    }

    // sd: full-wave reduce, one per owned slice; store is wave-exclusive.
    #pragma unroll
    for (int k = 0; k < 4; ++k) {
        float r = accd[k];
        r += __shfl_down(r, 32);
        r += __shfl_down(r, 16);
        r += __shfl_down(r, 8);
        r += __shfl_down(r, 4);
        r += __shfl_down(r, 2);
        r += __shfl_down(r, 1);
        if (l == 0) sd[k * 16 + wv] = r;
    }

    // sw: combine the 4 g-subgroups (same w4), then one atomic per w.
    #pragma unroll
    for (int jj = 0; jj < 4; ++jj) {
        float r = accw[jj];
        r += __shfl_down(r, 32);
        r += __shfl_down(r, 16);
        if (l < 16) atomicAdd(&sw[l * 4 + jj], r);
    }
    __syncthreads();

    if (t < 192) {
        float v = (t < 64) ? sd[t] : (t < 128) ? sh[t - 64] : sw[t - 128];
        const int n = blk >> 6, c = blk & 63;
        pool[(n * 192 + t) * 64 + c] = v * (1.0f / 4096.0f);
    }
}

// ============================================================================
// Kernel 2: per-(n,c) block. Stage A/B: recompute the tiny attention chain
// -> 192 gate values in LDS. Stage C: stream the cube:
// out = x * a[d] * a[64+h] * a[128+w]   (all f32).
// Round-1 configuration (best measured): NT load + NT store. Load policy was
// A/B-tested in rounds 1/2: nt vs regular load is noise; nt STORE is the win
// (out never re-read; don't evict x from the memory-side Infinity Cache).
// ============================================================================
__global__ __launch_bounds__(1024) void att_k(
    const float* __restrict__ x, const float* __restrict__ pool,
    const float* __restrict__ w1, const float* __restrict__ b1,
    const float* __restrict__ gam, const float* __restrict__ bet,
    const float* __restrict__ mu,  const float* __restrict__ var,
    const float* __restrict__ wd,  const float* __restrict__ bd,
    const float* __restrict__ wh,  const float* __restrict__ bh,
    const float* __restrict__ ww,  const float* __restrict__ bw,
    float* __restrict__ out)
{
    const int blk = blockIdx.x;
    const int n = blk >> 6, c = blk & 63;
    const int t = threadIdx.x;
    __shared__ float y_s[8][192];
    __shared__ float a_s[192];

    // ---- Stage A: y[m][l] = hardswish(BN(conv1(pool))) ----
    if (t < 192) {
        float acc[8] = {0,0,0,0,0,0,0,0};
        const float4* __restrict__ pp = (const float4*)(pool + (n * 192 + t) * 64);
        #pragma unroll 4
        for (int c4 = 0; c4 < 16; ++c4) {
            float4 p = pp[c4];
            const int cb = c4 * 4;
            #pragma unroll
            for (int m = 0; m < 8; ++m) {
                acc[m] += p.x * w1[m * 64 + cb]
                        + p.y * w1[m * 64 + cb + 1]
                        + p.z * w1[m * 64 + cb + 2]
                        + p.w * w1[m * 64 + cb + 3];
            }
        }
        #pragma unroll
        for (int m = 0; m < 8; ++m) {
            float scale = gam[m] * rsqrtf(var[m] + 1e-5f);
            float v = (acc[m] + b1[m] - mu[m]) * scale + bet[m];
            float hs = v * fminf(fmaxf(v + 3.0f, 0.0f), 6.0f) * (1.0f / 6.0f);
            y_s[m][t] = hs;
        }
    }
    __syncthreads();

    // ---- Stage B: gates a[l] = sigmoid(conv{d,h,w}(y)[o=c]) ----
    if (t < 192) {
        const float* wsel; float bsel;
        if (t < 64)       { wsel = wd + c * 8; bsel = bd[c]; }
        else if (t < 128) { wsel = wh + c * 8; bsel = bh[c]; }
        else              { wsel = ww + c * 8; bsel = bw[c]; }
        float v = bsel;
        #pragma unroll
        for (int m = 0; m < 8; ++m) v += y_s[m][t] * wsel[m];
        a_s[t] = 1.0f / (1.0f + __expf(-v));
    }
    __syncthreads();

    // ---- Stage C: out = x * ad*ah*aw, streamed (f32 in, f32 out) ----
    // float4 group g = t + k*1024: w4 = t&15, h = t>>4 loop-invariant; d = k.
    const int w4 = t & 15;
    const int h  = t >> 4;
    f32x4 gw;
    gw.x = a_s[128 + w4 * 4 + 0];
    gw.y = a_s[128 + w4 * 4 + 1];
    gw.z = a_s[128 + w4 * 4 + 2];
    gw.w = a_s[128 + w4 * 4 + 3];
    const float ahr = a_s[64 + h];
    const f32x4* __restrict__ xp = (const f32x4*)(x   + (size_t)blk * 262144);
    f32x4*       __restrict__ op = (f32x4*)      (out + (size_t)blk * 262144);

    #pragma unroll 2
    for (int k = 0; k < 64; ++k) {
        const int g = t + (k << 10);
        const float s = a_s[k] * ahr;        // a_s[d], d == k (uniform)
        f32x4 v = __builtin_nontemporal_load(&xp[g]);
        f32x4 o = v * (gw * s);
        __builtin_nontemporal_store(o, &op[g]);
    }
}

extern "C" void kernel_launch(void* const* d_in, const int* in_sizes, int n_in,
                              void* d_out, int out_size, void* d_ws, size_t ws_size,
                              hipStream_t stream) {
    const float* x = (const float*)d_in[0];
    float* pool = (float*)d_ws;   // 4*192*64 f32 = 192 KiB

    pool_k<<<256, 1024, 0, stream>>>(x, pool);
    att_k<<<256, 1024, 0, stream>>>(x, pool,
        (const float*)d_in[1],  (const float*)d_in[2],
        (const float*)d_in[3],  (const float*)d_in[4],
        (const float*)d_in[5],  (const float*)d_in[6],
        (const float*)d_in[7],  (const float*)d_in[8],
        (const float*)d_in[9],  (const float*)d_in[10],
        (const float*)d_in[11], (const float*)d_in[12],
        (float*)d_out);
}

// Round 4
// 506.441 us; speedup vs baseline: 1.0083x; 1.0046x over previous
//
#include <hip/hip_runtime.h>

typedef unsigned int uint;
typedef unsigned short ushort;
typedef float __attribute__((ext_vector_type(4))) f32x4;

// ============================================================================
// Kernel 1: per-(n,c) cube (64^3 f32 = 1 MB) -> xd[64], xh[64], xw[64] means.
// 1024 threads = 16 waves. Wave wv owns d-slices {wv, 16+wv, 32+wv, 48+wv}.
// FORWARD traversal: this pass warms the Infinity Cache with x; att_k below
// traverses in REVERSE so the re-read starts on the hottest (last-read) lines
// (x == 256 MiB == L3 capacity; forward re-read would LRU-cascade to ~0% hit).
// pool layout (f32, in d_ws): [n][l][c]; l: 0..63 = d, 64..127 = h,
// 128..191 = w. Transposed so kernel 2 reads rows with float4.
// ============================================================================
__global__ __launch_bounds__(1024) void pool_k(const float* __restrict__ x,
                                               float* __restrict__ pool) {
    const int blk = blockIdx.x;          // n*64 + c
    const int t  = threadIdx.x;
    const int wv = t >> 6;               // wave 0..15
    const int l  = t & 63;               // lane
    const int g  = l >> 4;               // 0..3  (h-subgroup)
    const int w4 = l & 15;               // w-quad
    __shared__ float sd[64], sh[64], sw[64];
    if (t < 64) { sh[t] = 0.f; sw[t] = 0.f; }
    __syncthreads();

    const float4* __restrict__ xp = (const float4*)(x + (size_t)blk * 262144);
    const float4* __restrict__ base = xp + wv * 1024 + l;

    float accd[4] = {0,0,0,0};           // per owned d-slice
    float accw[4] = {0,0,0,0};           // per w-in-quad component

    #pragma unroll 4
    for (int j = 0; j < 16; ++j) {       // h-row-quad within slice
        float acch = 0.f;
        #pragma unroll
        for (int k = 0; k < 4; ++k) {    // which owned slice (d = k*16+wv)
            float4 v = base[k * 16384 + j * 64];
            accw[0] += v.x; accw[1] += v.y; accw[2] += v.z; accw[3] += v.w;
            float s = (v.x + v.y) + (v.z + v.w);
            accd[k] += s;
            acch += s;
        }
        // reduce over the 16-lane w4 subgroup (h = j*4 + g is uniform there)
        acch += __shfl_xor(acch, 1);
        acch += __shfl_xor(acch, 2);
        acch += __shfl_xor(acch, 4);
        acch += __shfl_xor(acch, 8);
        if (w4 == 0) atomicAdd(&sh[j * 4 + g], acch);
    }

    // sd: full-wave reduce, one per owned slice; store is wave-exclusive.
    #pragma unroll
    for (int k = 0; k < 4; ++k) {
        float r = accd[k];
        r += __shfl_down(r, 32);
        r += __shfl_down(r, 16);
        r += __shfl_down(r, 8);
        r += __shfl_down(r, 4);
        r += __shfl_down(r, 2);
        r += __shfl_down(r, 1);
        if (l == 0) sd[k * 16 + wv] = r;
    }

    // sw: combine the 4 g-subgroups (same w4), then one atomic per w.
    #pragma unroll
    for (int jj = 0; jj < 4; ++jj) {
        float r = accw[jj];
        r += __shfl_down(r, 32);
        r += __shfl_down(r, 16);
        if (l < 16) atomicAdd(&sw[l * 4 + jj], r);
    }
    __syncthreads();

    if (t < 192) {
        float v = (t < 64) ? sd[t] : (t < 128) ? sh[t - 64] : sw[t - 128];
        const int n = blk >> 6, c = blk & 63;
        pool[(n * 192 + t) * 64 + c] = v * (1.0f / 4096.0f);
    }
}

// ============================================================================
// Kernel 2: per-(n,c) block. Stage A/B: recompute the tiny attention chain
// -> 192 gate values in LDS. Stage C: stream the cube:
// out = x * a[d] * a[64+h] * a[128+w]   (all f32).
// NT load + NT store (A/B-settled rounds 1/2: nt STORE is the win; load
// policy is noise). Stage C walks the cube in REVERSE d-order (k = 63..0):
// palindromic re-read of what pool_k just streamed, so the first touches hit
// the L3-resident tail instead of LRU-cascading from the evicted head.
// ============================================================================
__global__ __launch_bounds__(1024) void att_k(
    const float* __restrict__ x, const float* __restrict__ pool,
    const float* __restrict__ w1, const float* __restrict__ b1,
    const float* __restrict__ gam, const float* __restrict__ bet,
    const float* __restrict__ mu,  const float* __restrict__ var,
    const float* __restrict__ wd,  const float* __restrict__ bd,
    const float* __restrict__ wh,  const float* __restrict__ bh,
    const float* __restrict__ ww,  const float* __restrict__ bw,
    float* __restrict__ out)
{
    const int blk = blockIdx.x;
    const int n = blk >> 6, c = blk & 63;
    const int t = threadIdx.x;
    __shared__ float y_s[8][192];
    __shared__ float a_s[192];

    // ---- Stage A: y[m][l] = hardswish(BN(conv1(pool))) ----
    if (t < 192) {
        float acc[8] = {0,0,0,0,0,0,0,0};
        const float4* __restrict__ pp = (const float4*)(pool + (n * 192 + t) * 64);
        #pragma unroll 4
        for (int c4 = 0; c4 < 16; ++c4) {
            float4 p = pp[c4];
            const int cb = c4 * 4;
            #pragma unroll
            for (int m = 0; m < 8; ++m) {
                acc[m] += p.x * w1[m * 64 + cb]
                        + p.y * w1[m * 64 + cb + 1]
                        + p.z * w1[m * 64 + cb + 2]
                        + p.w * w1[m * 64 + cb + 3];
            }
        }
        #pragma unroll
        for (int m = 0; m < 8; ++m) {
            float scale = gam[m] * rsqrtf(var[m] + 1e-5f);
            float v = (acc[m] + b1[m] - mu[m]) * scale + bet[m];
            float hs = v * fminf(fmaxf(v + 3.0f, 0.0f), 6.0f) * (1.0f / 6.0f);
            y_s[m][t] = hs;
        }
    }
    __syncthreads();

    // ---- Stage B: gates a[l] = sigmoid(conv{d,h,w}(y)[o=c]) ----
    if (t < 192) {
        const float* wsel; float bsel;
        if (t < 64)       { wsel = wd + c * 8; bsel = bd[c]; }
        else if (t < 128) { wsel = wh + c * 8; bsel = bh[c]; }
        else              { wsel = ww + c * 8; bsel = bw[c]; }
        float v = bsel;
        #pragma unroll
        for (int m = 0; m < 8; ++m) v += y_s[m][t] * wsel[m];
        a_s[t] = 1.0f / (1.0f + __expf(-v));
    }
    __syncthreads();

    // ---- Stage C: out = x * ad*ah*aw, streamed in REVERSE d-order ----
    // float4 group g = t + k*1024: w4 = t&15, h = t>>4 loop-invariant; d = k.
    const int w4 = t & 15;
    const int h  = t >> 4;
    f32x4 gw;
    gw.x = a_s[128 + w4 * 4 + 0];
    gw.y = a_s[128 + w4 * 4 + 1];
    gw.z = a_s[128 + w4 * 4 + 2];
    gw.w = a_s[128 + w4 * 4 + 3];
    const float ahr = a_s[64 + h];
    const f32x4* __restrict__ xp = (const f32x4*)(x   + (size_t)blk * 262144);
    f32x4*       __restrict__ op = (f32x4*)      (out + (size_t)blk * 262144);

    #pragma unroll 2
    for (int k = 63; k >= 0; --k) {
        const int g = t + (k << 10);
        const float s = a_s[k] * ahr;        // a_s[d], d == k (uniform)
        f32x4 v = __builtin_nontemporal_load(&xp[g]);
        f32x4 o = v * (gw * s);
        __builtin_nontemporal_store(o, &op[g]);
    }
}

extern "C" void kernel_launch(void* const* d_in, const int* in_sizes, int n_in,
                              void* d_out, int out_size, void* d_ws, size_t ws_size,
                              hipStream_t stream) {
    const float* x = (const float*)d_in[0];
    float* pool = (float*)d_ws;   // 4*192*64 f32 = 192 KiB

    pool_k<<<256, 1024, 0, stream>>>(x, pool);
    att_k<<<256, 1024, 0, stream>>>(x, pool,
        (const float*)d_in[1],  (const float*)d_in[2],
        (const float*)d_in[3],  (const float*)d_in[4],
        (const float*)d_in[5],  (const float*)d_in[6],
        (const float*)d_in[7],  (const float*)d_in[8],
        (const float*)d_in[9],  (const float*)d_in[10],
        (const float*)d_in[11], (const float*)d_in[12],
        (float*)d_out);
}